// Round 1
// 425.211 us; speedup vs baseline: 1.0178x; 1.0178x over previous
//
#include <hip/hip_runtime.h>

#define D_MODEL 768
#define BN 16
#define NROWS 32768
#define SCALE 0.1f
#define LN_EPS 1e-5f
#define TPB 256
#define JPT 3                       // d's per thread: 768/256
#define ROWS_PER_BLOCK 32
#define NBLOCKS (NROWS / ROWS_PER_BLOCK)   // 1024

// Raw barrier: LDS-visibility only (no vmcnt(0) drain => global loads/stores
// stay in flight across the barrier). sched_barrier(0) prevents the compiler
// hoisting dependent LDS reads above the barrier (guide rule #18).
__device__ __forceinline__ void block_barrier_lgkm() {
    asm volatile("s_waitcnt lgkmcnt(0)" ::: "memory");
    __builtin_amdgcn_s_barrier();
    __builtin_amdgcn_sched_barrier(0);
}

__global__ __launch_bounds__(TPB, 2)
void adapter_fused(const float* __restrict__ x,
                   const float* __restrict__ gamma,
                   const float* __restrict__ beta,
                   const float* __restrict__ w_down,
                   const float* __restrict__ b_down,
                   const float* __restrict__ w_up,
                   const float* __restrict__ b_up,
                   float* __restrict__ out)
{
    __shared__ float s_ln[4][2];                     // per-wave (s1, s2)
    __shared__ __align__(16) float s_dpart[4][BN];   // per-wave down partials

    const int t    = threadIdx.x;
    const int wave = t >> 6;
    const int lane = t & 63;

    // ---- one-time per block: weights & params into registers ----
    float wd[JPT][BN];   // w_down[d][k], d = t + 256*j   (row-major (768,16))
    float wu[JPT][BN];   // w_up[k][d]                    (row-major (16,768))
    float g[JPT], bt[JPT], bu[JPT];
    #pragma unroll
    for (int j = 0; j < JPT; ++j) {
        const int d = t + TPB * j;
        const float4* wrow = (const float4*)(w_down + (size_t)d * BN);
        #pragma unroll
        for (int q = 0; q < 4; ++q) {
            float4 v = wrow[q];
            wd[j][q*4+0] = v.x; wd[j][q*4+1] = v.y;
            wd[j][q*4+2] = v.z; wd[j][q*4+3] = v.w;
        }
        #pragma unroll
        for (int k = 0; k < BN; ++k)
            wu[j][k] = w_up[k * D_MODEL + d];
        g[j]  = gamma[d];
        bt[j] = beta[d];
        bu[j] = b_up[d];
    }
    float bdk[BN];
    {
        const float4* bq = (const float4*)b_down;
        #pragma unroll
        for (int q = 0; q < 4; ++q) {
            float4 v = bq[q];
            bdk[q*4+0] = v.x; bdk[q*4+1] = v.y;
            bdk[q*4+2] = v.z; bdk[q*4+3] = v.w;
        }
    }

    // ---- PIN block-invariants in VGPRs: forbids the compiler from
    // rematerializing these loads inside the row loop (VGPR=92 in the
    // baseline proves it reloaded ~96 weight words per thread PER ROW).
    // Budget: launch_bounds(256,2) => 256 VGPRs; live set ~190 => no spill.
    #pragma unroll
    for (int j = 0; j < JPT; ++j) {
        #pragma unroll
        for (int k = 0; k < BN; ++k)
            asm volatile("" : "+v"(wd[j][k]), "+v"(wu[j][k]));
        asm volatile("" : "+v"(g[j]), "+v"(bt[j]), "+v"(bu[j]));
    }
    #pragma unroll
    for (int k = 0; k < BN; ++k)
        asm volatile("" : "+v"(bdk[k]));

    const float inv_d = 1.0f / (float)D_MODEL;
    const int row0 = blockIdx.x * ROWS_PER_BLOCK;

    // prologue: load row 0
    float xv[JPT];
    {
        const float* xr = x + (size_t)row0 * D_MODEL;
        #pragma unroll
        for (int j = 0; j < JPT; ++j) xv[j] = xr[t + TPB * j];
    }

    for (int r = 0; r < ROWS_PER_BLOCK; ++r) {
        float* __restrict__ orow = out + (size_t)(row0 + r) * D_MODEL;

        // ---- LayerNorm stats: wave butterfly + cross-wave via LDS ----
        float s1 = 0.f, s2 = 0.f;
        #pragma unroll
        for (int j = 0; j < JPT; ++j) { s1 += xv[j]; s2 = fmaf(xv[j], xv[j], s2); }
        #pragma unroll
        for (int m = 32; m >= 1; m >>= 1) {
            s1 += __shfl_xor(s1, m, 64);
            s2 += __shfl_xor(s2, m, 64);
        }
        if (lane == 0) { s_ln[wave][0] = s1; s_ln[wave][1] = s2; }

        block_barrier_lgkm();                       // bar1: s_ln ready

        const float S1 = s_ln[0][0] + s_ln[1][0] + s_ln[2][0] + s_ln[3][0];
        const float S2 = s_ln[0][1] + s_ln[1][1] + s_ln[2][1] + s_ln[3][1];
        const float mean = S1 * inv_d;
        const float var  = fmaf(S2, inv_d, -(mean * mean));
        const float rs   = rsqrtf(var + LN_EPS);

        // ---- prefetch next row's x; latency hides under down-proj +
        // butterfly + bar2 (+no vmcnt drain at our raw barriers) ----
        float xpf[JPT];
        {
            const int rn = (r + 1 < ROWS_PER_BLOCK) ? (r + 1) : r;
            const float* xrn = x + (size_t)(row0 + rn) * D_MODEL;
            #pragma unroll
            for (int j = 0; j < JPT; ++j) xpf[j] = xrn[t + TPB * j];
        }

        // ---- normalize + down-proj partials (48 FMA) ----
        float xn[JPT];
        #pragma unroll
        for (int j = 0; j < JPT; ++j)
            xn[j] = fmaf((xv[j] - mean) * rs, g[j], bt[j]);

        float p[BN];
        #pragma unroll
        for (int k = 0; k < BN; ++k) p[k] = 0.f;
        #pragma unroll
        for (int j = 0; j < JPT; ++j) {
            #pragma unroll
            for (int k = 0; k < BN; ++k)
                p[k] = fmaf(xn[j], wd[j][k], p[k]);
        }

        // ---- split-butterfly: 16-vector reduced across 16 lanes in 15 shfls;
        //      then 2 more for the wave-level sum of k = lane&15 ----
        #pragma unroll
        for (int m = 8; m >= 1; m >>= 1) {
            const bool upper = (lane & m) != 0;
            #pragma unroll
            for (int i = 0; i < m; ++i) {
                float send = upper ? p[i] : p[i + m];
                float recv = __shfl_xor(send, m, 64);
                p[i] = (upper ? p[i + m] : p[i]) + recv;
            }
        }
        float v = p[0];
        v += __shfl_xor(v, 16, 64);
        v += __shfl_xor(v, 32, 64);

        if (lane < BN) s_dpart[wave][lane] = v;

        block_barrier_lgkm();                       // bar2: s_dpart ready

        // ---- every thread finishes the down vector itself (removes the old
        // t<16 stage + third barrier). 16 broadcast ds_read_b128, free. ----
        float dn[BN];
        {
            const float4* sp = (const float4*)(&s_dpart[0][0]);
            #pragma unroll
            for (int q = 0; q < 4; ++q) {
                float4 a = sp[q];
                float4 b = sp[4 + q];
                float4 c = sp[8 + q];
                float4 e = sp[12 + q];
                dn[q*4+0] = fmaxf(a.x + b.x + c.x + e.x + bdk[q*4+0], 0.f);
                dn[q*4+1] = fmaxf(a.y + b.y + c.y + e.y + bdk[q*4+1], 0.f);
                dn[q*4+2] = fmaxf(a.z + b.z + c.z + e.z + bdk[q*4+2], 0.f);
                dn[q*4+3] = fmaxf(a.w + b.w + c.w + e.w + bdk[q*4+3], 0.f);
            }
        }

        // ---- up-proj (48 FMA) + scale + residual, coalesced store ----
        #pragma unroll
        for (int j = 0; j < JPT; ++j) {
            float acc = bu[j];
            #pragma unroll
            for (int k = 0; k < BN; ++k)
                acc = fmaf(dn[k], wu[j][k], acc);
            orow[t + TPB * j] = fmaf(SCALE, acc, xv[j]);
        }

        // rotate prefetched row in
        #pragma unroll
        for (int j = 0; j < JPT; ++j) xv[j] = xpf[j];
    }
}

extern "C" void kernel_launch(void* const* d_in, const int* in_sizes, int n_in,
                              void* d_out, int out_size, void* d_ws, size_t ws_size,
                              hipStream_t stream) {
    const float* x       = (const float*)d_in[0];
    const float* gamma   = (const float*)d_in[1];
    const float* beta    = (const float*)d_in[2];
    const float* w_down  = (const float*)d_in[3];
    const float* b_down  = (const float*)d_in[4];
    const float* w_up    = (const float*)d_in[5];
    const float* b_up    = (const float*)d_in[6];
    float* out = (float*)d_out;

    adapter_fused<<<NBLOCKS, TPB, 0, stream>>>(x, gamma, beta, w_down, b_down,
                                               w_up, b_up, out);
}

// Round 2
// 204.020 us; speedup vs baseline: 2.1212x; 2.0842x over previous
//
#include <hip/hip_runtime.h>

#define D_MODEL 768
#define BN 16
#define NROWS 32768
#define SCALE 0.1f
#define LN_EPS 1e-5f
#define TPB 1024
#define WAVES 16
#define DPL 12                               // d's per lane (768/64)
#define PASSES 2
#define ROWS_PER_BLOCK (WAVES * 2 * PASSES)  // 64
#define NBLOCKS (NROWS / ROWS_PER_BLOCK)     // 512

__device__ __forceinline__ void ld4(const float* p, float* d) {
    float4 v = *(const float4*)p;
    d[0] = v.x; d[1] = v.y; d[2] = v.z; d[3] = v.w;
}

__global__ __launch_bounds__(TPB)
void adapter_fused(const float* __restrict__ x,
                   const float* __restrict__ gamma,
                   const float* __restrict__ beta,
                   const float* __restrict__ w_down,
                   const float* __restrict__ b_down,
                   const float* __restrict__ w_up,
                   const float* __restrict__ b_up,
                   float* __restrict__ out)
{
    // Weights + params staged ONCE per block. 107 KB => 1 block/CU, 16 waves.
    __shared__ __align__(16) float s_wdT[BN * D_MODEL];   // [k][d]  48 KB
    __shared__ __align__(16) float s_wu [BN * D_MODEL];   // [k][d]  48 KB
    __shared__ __align__(16) float s_g  [D_MODEL];
    __shared__ __align__(16) float s_bt [D_MODEL];
    __shared__ __align__(16) float s_buv[D_MODEL];
    __shared__ __align__(16) float s_bd [BN];
    __shared__ __align__(16) float s_dn [WAVES][2][BN];   // per-wave scratch

    const int t    = threadIdx.x;
    const int w    = t >> 6;
    const int lane = t & 63;

    // ---------------- one-time staging ----------------
    if (t < D_MODEL) {
        // transpose w_down (768,16) -> s_wdT[k][d]
        const float4* wr = (const float4*)(w_down + (size_t)t * BN);
        #pragma unroll
        for (int q = 0; q < 4; ++q) {
            float4 v = wr[q];
            s_wdT[(q*4+0)*D_MODEL + t] = v.x;
            s_wdT[(q*4+1)*D_MODEL + t] = v.y;
            s_wdT[(q*4+2)*D_MODEL + t] = v.z;
            s_wdT[(q*4+3)*D_MODEL + t] = v.w;
        }
        s_g[t]   = gamma[t];
        s_bt[t]  = beta[t];
        s_buv[t] = b_up[t];
    }
    {   // w_up (16,768) row-major -> straight copy, 3072 float4
        const float4* src = (const float4*)w_up;
        float4* dst = (float4*)s_wu;
        #pragma unroll
        for (int q = 0; q < 3; ++q) dst[t + q * TPB] = src[t + q * TPB];
    }
    if (t < BN) s_bd[t] = b_down[t];
    __syncthreads();            // the ONLY block-wide barrier

    const int   base = lane * DPL;        // this lane's d-range [base, base+12)
    const float* wdp = s_wdT + base;
    const float* wup = s_wu  + base;
    const float inv_d = 1.0f / (float)D_MODEL;

    for (int pp = 0; pp < PASSES; ++pp) {
        const int r0 = blockIdx.x * ROWS_PER_BLOCK + pp * (WAVES * 2) + w * 2;
        const float* xp0 = x + (size_t)r0 * D_MODEL + base;
        const float* xp1 = xp0 + D_MODEL;

        // ---- load 2 rows (48 B/lane contiguous => dwordx4 coalesced) ----
        float xa[DPL], xb[DPL];
        ld4(xp0 + 0, xa + 0); ld4(xp0 + 4, xa + 4); ld4(xp0 + 8, xa + 8);
        ld4(xp1 + 0, xb + 0); ld4(xp1 + 4, xb + 4); ld4(xp1 + 8, xb + 8);

        // ---- LN stats, fully in-wave ----
        float s1a = 0.f, s2a = 0.f, s1b = 0.f, s2b = 0.f;
        #pragma unroll
        for (int i = 0; i < DPL; ++i) {
            s1a += xa[i]; s2a = fmaf(xa[i], xa[i], s2a);
            s1b += xb[i]; s2b = fmaf(xb[i], xb[i], s2b);
        }
        #pragma unroll
        for (int m = 32; m >= 1; m >>= 1) {
            s1a += __shfl_xor(s1a, m, 64); s2a += __shfl_xor(s2a, m, 64);
            s1b += __shfl_xor(s1b, m, 64); s2b += __shfl_xor(s2b, m, 64);
        }
        const float ma  = s1a * inv_d;
        const float rsa = rsqrtf(fmaf(s2a, inv_d, -(ma * ma)) + LN_EPS);
        const float mb  = s1b * inv_d;
        const float rsb = rsqrtf(fmaf(s2b, inv_d, -(mb * mb)) + LN_EPS);

        // ---- normalize (gamma/beta from LDS, conflict-free stride-48) ----
        float g_[DPL], bt_[DPL];
        ld4(s_g  + base + 0, g_  + 0); ld4(s_g  + base + 4, g_  + 4); ld4(s_g  + base + 8, g_  + 8);
        ld4(s_bt + base + 0, bt_ + 0); ld4(s_bt + base + 4, bt_ + 4); ld4(s_bt + base + 8, bt_ + 8);
        float na[DPL], nb[DPL];
        #pragma unroll
        for (int i = 0; i < DPL; ++i) {
            na[i] = fmaf((xa[i] - ma) * rsa, g_[i], bt_[i]);
            nb[i] = fmaf((xb[i] - mb) * rsb, g_[i], bt_[i]);
        }
        // xa/xb dead here (residual re-reads x from L2 later) => low reg peak

        // ---- down-proj: weights from LDS, shared by BOTH rows ----
        float p0[BN], p1[BN];
        #pragma unroll
        for (int k = 0; k < BN; ++k) { p0[k] = 0.f; p1[k] = 0.f; }
        #pragma unroll
        for (int k = 0; k < BN; ++k) {
            float wv[DPL];
            ld4(wdp + k * D_MODEL + 0, wv + 0);
            ld4(wdp + k * D_MODEL + 4, wv + 4);
            ld4(wdp + k * D_MODEL + 8, wv + 8);
            #pragma unroll
            for (int i = 0; i < DPL; ++i) {
                p0[k] = fmaf(na[i], wv[i], p0[k]);
                p1[k] = fmaf(nb[i], wv[i], p1[k]);
            }
        }

        // ---- in-wave split-butterfly reduce of p[16] ----
        #pragma unroll
        for (int m = 8; m >= 1; m >>= 1) {
            const bool up = (lane & m) != 0;
            #pragma unroll
            for (int i = 0; i < m; ++i) {
                float sa = up ? p0[i] : p0[i + m];
                float sb = up ? p1[i] : p1[i + m];
                float ra = __shfl_xor(sa, m, 64);
                float rb = __shfl_xor(sb, m, 64);
                p0[i] = (up ? p0[i + m] : p0[i]) + ra;
                p1[i] = (up ? p1[i + m] : p1[i]) + rb;
            }
        }
        float va = p0[0];
        va += __shfl_xor(va, 16, 64); va += __shfl_xor(va, 32, 64);
        float vb = p1[0];
        vb += __shfl_xor(vb, 16, 64); vb += __shfl_xor(vb, 32, 64);

        // ---- bias + ReLU, stash in per-wave LDS (no block barrier) ----
        if (lane < BN) {
            const float bd = s_bd[lane];
            s_dn[w][0][lane] = fmaxf(va + bd, 0.f);
            s_dn[w][1][lane] = fmaxf(vb + bd, 0.f);
        }

        // issue residual x reload early (L2-warm); hides under up-proj
        float ra0[DPL], ra1[DPL];
        ld4(xp0 + 0, ra0 + 0); ld4(xp0 + 4, ra0 + 4); ld4(xp0 + 8, ra0 + 8);
        ld4(xp1 + 0, ra1 + 0); ld4(xp1 + 4, ra1 + 4); ld4(xp1 + 8, ra1 + 8);

        // same-wave DS ordering + keep compiler from hoisting the reads
        asm volatile("s_waitcnt lgkmcnt(0)" ::: "memory");
        __builtin_amdgcn_sched_barrier(0);

        float dn0[BN], dn1[BN];
        ld4(&s_dn[w][0][0], dn0 + 0);  ld4(&s_dn[w][0][4], dn0 + 4);
        ld4(&s_dn[w][0][8], dn0 + 8);  ld4(&s_dn[w][0][12], dn0 + 12);
        ld4(&s_dn[w][1][0], dn1 + 0);  ld4(&s_dn[w][1][4], dn1 + 4);
        ld4(&s_dn[w][1][8], dn1 + 8);  ld4(&s_dn[w][1][12], dn1 + 12);

        // ---- up-proj: acc starts at b_up; weights shared by both rows ----
        float a0[DPL], a1[DPL];
        {
            float bu_[DPL];
            ld4(s_buv + base + 0, bu_ + 0);
            ld4(s_buv + base + 4, bu_ + 4);
            ld4(s_buv + base + 8, bu_ + 8);
            #pragma unroll
            for (int i = 0; i < DPL; ++i) { a0[i] = bu_[i]; a1[i] = bu_[i]; }
        }
        #pragma unroll
        for (int k = 0; k < BN; ++k) {
            float wv[DPL];
            ld4(wup + k * D_MODEL + 0, wv + 0);
            ld4(wup + k * D_MODEL + 4, wv + 4);
            ld4(wup + k * D_MODEL + 8, wv + 8);
            #pragma unroll
            for (int i = 0; i < DPL; ++i) {
                a0[i] = fmaf(dn0[k], wv[i], a0[i]);
                a1[i] = fmaf(dn1[k], wv[i], a1[i]);
            }
        }

        // ---- scale + residual, coalesced float4 stores ----
        float* op0 = out + (size_t)r0 * D_MODEL + base;
        float* op1 = op0 + D_MODEL;
        #pragma unroll
        for (int q = 0; q < 3; ++q) {
            float4 o0, o1;
            o0.x = fmaf(SCALE, a0[q*4+0], ra0[q*4+0]);
            o0.y = fmaf(SCALE, a0[q*4+1], ra0[q*4+1]);
            o0.z = fmaf(SCALE, a0[q*4+2], ra0[q*4+2]);
            o0.w = fmaf(SCALE, a0[q*4+3], ra0[q*4+3]);
            o1.x = fmaf(SCALE, a1[q*4+0], ra1[q*4+0]);
            o1.y = fmaf(SCALE, a1[q*4+1], ra1[q*4+1]);
            o1.z = fmaf(SCALE, a1[q*4+2], ra1[q*4+2]);
            o1.w = fmaf(SCALE, a1[q*4+3], ra1[q*4+3]);
            ((float4*)op0)[q] = o0;
            ((float4*)op1)[q] = o1;
        }
    }
}

extern "C" void kernel_launch(void* const* d_in, const int* in_sizes, int n_in,
                              void* d_out, int out_size, void* d_ws, size_t ws_size,
                              hipStream_t stream) {
    const float* x       = (const float*)d_in[0];
    const float* gamma   = (const float*)d_in[1];
    const float* beta    = (const float*)d_in[2];
    const float* w_down  = (const float*)d_in[3];
    const float* b_down  = (const float*)d_in[4];
    const float* w_up    = (const float*)d_in[5];
    const float* b_up    = (const float*)d_in[6];
    float* out = (float*)d_out;

    adapter_fused<<<NBLOCKS, TPB, 0, stream>>>(x, gamma, beta, w_down, b_down,
                                               w_up, b_up, out);
}